// Round 11
// baseline (532.757 us; speedup 1.0000x reference)
//
#include <hip/hip_runtime.h>
#include <hip/hip_bf16.h>
#include <math.h>

#define BATCH 128
#define NCH 19
#define TLEN 1000
#define NNODES (BATCH * NCH)

// branch-free ELU via hardware v_exp_f32: exact for x>=0, |err|<=~1e-7 for x<0
__device__ __forceinline__ float eluf(float x) {
  return fmaxf(x, 0.f) + (__expf(fminf(x, 0.f)) - 1.f);
}
__device__ __forceinline__ float geluf(float x) { return 0.5f * x * (1.f + erff(x * 0.70710678118654752f)); }
__device__ __forceinline__ float sigf(float x) { return 1.f / (1.f + __expf(-x)); }
__device__ __forceinline__ float lrelu(float x) { return x > 0.f ? x : 0.2f * x; }

// ---------------------------------------------------------------------------
// K1: multiscale conv1d, three sequential passes (register-demand-capped;
// round 10: VGPR 48, no spill, 138 us). Writes ONLY feat[n*32+16..31] (z).
// grid: NNODES blocks
// ---------------------------------------------------------------------------
#define RP 8
__global__ __launch_bounds__(256) void k_ms(
    const float* __restrict__ x, const float* __restrict__ w0,
    const float* __restrict__ ga0, const float* __restrict__ bb0,
    const float* __restrict__ w1, const float* __restrict__ ga1,
    const float* __restrict__ bb1, const float* __restrict__ w2,
    const float* __restrict__ ga2, const float* __restrict__ bb2,
    float* __restrict__ feat) {
  int n = blockIdx.x, tid = threadIdx.x;
  __shared__ float xr[1034];  // xr[i] = x[n, i-17], zero padded
  __shared__ float wst[1200]; // w0(240) | w1(400) | w2(560)
  __shared__ float red[256];
  for (int i = tid; i < 1034; i += 256) {
    int t = i - 17;
    xr[i] = (t >= 0 && t < TLEN) ? x[(size_t)n * TLEN + t] : 0.f;
  }
  for (int i = tid; i < 240; i += 256) wst[i] = w0[i];
  for (int i = tid; i < 400; i += 256) wst[240 + i] = w1[i];
  for (int i = tid; i < 560; i += 256) wst[640 + i] = w2[i];
  __syncthreads();

  int f = tid & 15, plane = tid >> 4;
  float z = 0.f;

  {  // pass 0: kernel 15
    float w[15];
#pragma unroll
    for (int k = 0; k < 15; k++) w[k] = wst[f * 15 + k];
    float g = ga0[f], c = bb0[f];
    for (int base = plane * RP; base < TLEN; base += 16 * RP) {
      float xv[14 + RP];
#pragma unroll
      for (int i = 0; i < 14 + RP; i++) xv[i] = xr[base + 10 + i];
#pragma unroll
      for (int r = 0; r < RP; r++) {
        float a = 0.f;
#pragma unroll
        for (int k = 0; k < 15; k++) a += xv[r + k] * w[k];
        z += eluf(g * a + c);
      }
    }
  }
  {  // pass 1: kernel 25
    float w[25];
#pragma unroll
    for (int k = 0; k < 25; k++) w[k] = wst[240 + f * 25 + k];
    float g = ga1[f], c = bb1[f];
    for (int base = plane * RP; base < TLEN; base += 16 * RP) {
      float xv[24 + RP];
#pragma unroll
      for (int i = 0; i < 24 + RP; i++) xv[i] = xr[base + 5 + i];
#pragma unroll
      for (int r = 0; r < RP; r++) {
        float a = 0.f;
#pragma unroll
        for (int k = 0; k < 25; k++) a += xv[r + k] * w[k];
        z += eluf(g * a + c);
      }
    }
  }
  {  // pass 2: kernel 35
    float w[35];
#pragma unroll
    for (int k = 0; k < 35; k++) w[k] = wst[640 + f * 35 + k];
    float g = ga2[f], c = bb2[f];
    for (int base = plane * RP; base < TLEN; base += 16 * RP) {
      float xv[34 + RP];
#pragma unroll
      for (int i = 0; i < 34 + RP; i++) xv[i] = xr[base + i];
#pragma unroll
      for (int r = 0; r < RP; r++) {
        float a = 0.f;
#pragma unroll
        for (int k = 0; k < 35; k++) a += xv[r + k] * w[k];
        z += eluf(g * a + c);
      }
    }
  }

  red[tid] = z;
  __syncthreads();
  for (int s = 128; s >= 16; s >>= 1) {
    if (tid < s) red[tid] += red[tid + s];
    __syncthreads();
  }
  if (tid < 16) feat[(size_t)n * 32 + 16 + tid] = red[tid] * (1.f / 3000.f);
}

// ---------------------------------------------------------------------------
// K2: FUSED per-batch kernel: frontend (depthwise+conv25+bn+elu, SE, pool4,
// sep-conv+bn+elu+mean) + GAT1 + GAT2 + pool + classifier.
// One 63.8 KB LDS arena with phase-wise region reuse (offsets below, lifetimes
// hand-verified). x read from HBM exactly once per block; GAT1 output stays
// in LDS; only global traffic besides weights is feat's z-half (from k_ms).
// grid: B blocks, 256 thr
// ---------------------------------------------------------------------------
// Region offsets (floats) in S[16336]:
//  frontend: XW 0..8199 (8x1025) | Y4 8200..12231 (16x252) | DWS 12232 (304)
//            W1S 12536 (400) | SS 12936 (16) | SE 12952 (16) | U4 12968 (4)
//            RED 12992 (32)
//  sep:      SWS 0..4095 (xw dead) | Y4, SS/SE live | YV 16320 (16)
//  GAT:      FB 0 (608) | H 608 (9728) | WATT 10336 (2888) | AS 13224 (152)
//            AD 13376 (152) | SC 13528 (19) | HB 13548 (1216)
//            HOUT 14764 (1216) | GP 15980 (64) | US 16044 (64) | YV 16320
#define OF_XW 0
#define OF_Y4 8200
#define OF_DWS 12232
#define OF_W1S 12536
#define OF_SS 12936
#define OF_SE 12952
#define OF_U4 12968
#define OF_RED 12992
#define OF_SWS 0
#define OF_FB 0
#define OF_H 608
#define OF_WATT 10336
#define OF_AS 13224
#define OF_AD 13376
#define OF_SC 13528
#define OF_HB 13548
#define OF_HOUT 14764
#define OF_GP 15980
#define OF_US 16044
#define OF_YV 16320

__global__ __launch_bounds__(256) void k_fused(
    const float* __restrict__ x, const float* __restrict__ w1,
    const float* __restrict__ bn1g, const float* __restrict__ bn1b,
    const float* __restrict__ dw, const float* __restrict__ bn2g,
    const float* __restrict__ bn2b, const float* __restrict__ sew1,
    const float* __restrict__ sew2, const float* __restrict__ sw,
    const float* __restrict__ g3, const float* __restrict__ b3,
    const float* __restrict__ adjw, const float* __restrict__ adjb,
    const float* __restrict__ g1w, const float* __restrict__ g1as,
    const float* __restrict__ g1ad, const float* __restrict__ g1bias,
    const float* __restrict__ skw, const float* __restrict__ skb,
    const float* __restrict__ bg1, const float* __restrict__ bb1g,
    const float* __restrict__ g2w, const float* __restrict__ g2as,
    const float* __restrict__ g2ad, const float* __restrict__ g2bias,
    const float* __restrict__ bg2, const float* __restrict__ bb2g,
    const float* __restrict__ cw1, const float* __restrict__ cb1,
    const float* __restrict__ cw2, const float* __restrict__ cb2,
    const float* __restrict__ feat, float* __restrict__ out) {
  __shared__ float S[16336];
  int b = blockIdx.x, tid = threadIdx.x;
  int lane = tid & 63, wid = tid >> 6;

  // ---- stage depthwise + conv1 weights
  for (int i = tid; i < 304; i += 256) S[OF_DWS + i] = dw[i];
  for (int i = tid; i < 400; i += 256) S[OF_W1S + i] = w1[i];
  __syncthreads();

  const float* xb = x + (size_t)b * NCH * TLEN;
  // ---- frontend: two halves of 8 filters
  for (int half = 0; half < 2; half++) {
    // phase A: xw for 8 filters (x read from global exactly once overall)
    for (int i = tid; i < 1024; i += 256) {
      int t = i - 12;
      float xv[19];
      if (t >= 0 && t < TLEN) {
#pragma unroll
        for (int c = 0; c < 19; c++) xv[c] = xb[c * TLEN + t];
      } else {
#pragma unroll
        for (int c = 0; c < 19; c++) xv[c] = 0.f;
      }
#pragma unroll
      for (int fo = 0; fo < 8; fo++) {
        const float* dr = &S[OF_DWS + (half * 8 + fo) * 19];
        float a = 0.f;
#pragma unroll
        for (int c = 0; c < 19; c++) a += dr[c] * xv[c];
        S[OF_XW + fo * 1025 + i] = a;
      }
    }
    __syncthreads();
    // phase B: conv25 + bn + elu + pool4 -> Y4; per-thread squeeze partials
    float pools[8];
#pragma unroll
    for (int fo = 0; fo < 8; fo++) pools[fo] = 0.f;
    if (tid < 250) {
#pragma unroll
      for (int fo = 0; fo < 8; fo++) {
        int f = half * 8 + fo;
        float scale = bn2g[f] * bn1g[f];
        float sumdw = 0.f;
#pragma unroll
        for (int c = 0; c < 19; c++) sumdw += S[OF_DWS + f * 19 + c];
        float cb = bn2g[f] * bn1b[f] * sumdw + bn2b[f];
        const float* wr = &S[OF_W1S + f * 25];
        float win[28];
#pragma unroll
        for (int i2 = 0; i2 < 28; i2++)
          win[i2] = S[OF_XW + fo * 1025 + 4 * tid + i2];
        float pool = 0.f;
#pragma unroll
        for (int q = 0; q < 4; q++) {
          float acc = 0.f;
#pragma unroll
          for (int k = 0; k < 25; k++) acc += wr[k] * win[q + k];
          pool += eluf(scale * acc + cb);
        }
        pools[fo] = pool;
        S[OF_Y4 + f * 252 + tid] = pool * 0.25f;
      }
    }
#pragma unroll
    for (int fo = 0; fo < 8; fo++) {
      float v = pools[fo];
      for (int off = 32; off > 0; off >>= 1) v += __shfl_down(v, off, 64);
      if (lane == 0) S[OF_RED + wid * 8 + fo] = v;
    }
    __syncthreads();
    if (tid < 8)
      S[OF_SS + half * 8 + tid] =
          (S[OF_RED + tid] + S[OF_RED + 8 + tid] + S[OF_RED + 16 + tid] +
           S[OF_RED + 24 + tid]) * (1.f / 1000.f);
    __syncthreads();
  }
  // ---- SE MLP
  if (tid < 4) {
    float a = 0.f;
#pragma unroll
    for (int ff = 0; ff < 16; ff++) a += S[OF_SS + ff] * sew1[ff * 4 + tid];
    S[OF_U4 + tid] = geluf(a);
  }
  __syncthreads();
  if (tid < 16) {
    float a = 0.f;
#pragma unroll
    for (int j = 0; j < 4; j++) a += S[OF_U4 + j] * sew2[j * 16 + tid];
    S[OF_SE + tid] = sigf(a);
  }
  __syncthreads();
  for (int idx = tid; idx < 4000; idx += 256) {
    int f = idx / 250, p = idx - f * 250;
    S[OF_Y4 + f * 252 + p] *= S[OF_SE + f];
  }
  for (int i = tid; i < 4096; i += 256) S[OF_SWS + i] = sw[i];  // xw dead
  __syncthreads();
  // ---- sep conv (k=16, pad 8) + bn3 + elu + mean over 251 -> YV
  {
    int fo = tid >> 4, l16 = tid & 15;
    float g3v = g3[fo], b3v = b3[fo];
    float accsum = 0.f;
    for (int o = l16; o < 251; o += 16) {
      float acc = 0.f;
      int klo = (o < 8) ? (8 - o) : 0;
      int khi = (258 - o < 16) ? (258 - o) : 16;
      for (int fi = 0; fi < 16; fi++) {
        const float* yr = &S[OF_Y4 + fi * 252 + o - 8];
        const float* wp = &S[OF_SWS + fo * 256 + fi * 16];
        for (int k = klo; k < khi; k++) acc += yr[k] * wp[k];
      }
      accsum += eluf(g3v * acc + b3v);
    }
    accsum += __shfl_down(accsum, 8, 16);
    accsum += __shfl_down(accsum, 4, 16);
    accsum += __shfl_down(accsum, 2, 16);
    accsum += __shfl_down(accsum, 1, 16);
    if (l16 == 0) S[OF_YV + fo] = accsum * (1.f / 251.f);
  }
  __syncthreads();

  // ---- GAT layer 1
  float* fb = &S[OF_FB];
  float* h = &S[OF_H];
  float* watt = &S[OF_WATT];
  float* as_s = &S[OF_AS];
  float* ad_s = &S[OF_AD];
  float* sc_s = &S[OF_SC];
  float* hb = &S[OF_HB];
  float* hout = &S[OF_HOUT];
  for (int idx = tid; idx < 19 * 32; idx += 256) {
    int i = idx >> 5, c = idx & 31;
    fb[idx] = (c < 16) ? S[OF_YV + c] : feat[(size_t)(b * 19 + i) * 32 + c];
  }
  __syncthreads();
  for (int idx = tid; idx < 19 * 512; idx += 256) {
    int i = idx >> 9, o = idx & 511;
    const float* fr = &fb[i * 32];
    float a = 0.f;
#pragma unroll
    for (int c = 0; c < 32; c++) a += fr[c] * g1w[c * 512 + o];
    h[idx] = a;
  }
  if (tid < 19) {
    float a = adjb[0];
#pragma unroll
    for (int c = 0; c < 32; c++) a += fb[tid * 32 + c] * adjw[c];
    sc_s[tid] = sigf(a);
  }
  __syncthreads();
  if (tid < 152) {
    int i = tid / 8, hh = tid & 7;
    float a = 0.f, d2 = 0.f;
#pragma unroll
    for (int d = 0; d < 64; d++) {
      float hv = h[i * 512 + hh * 64 + d];
      a += hv * g1as[hh * 64 + d];
      d2 += hv * g1ad[hh * 64 + d];
    }
    as_s[tid] = a;
    ad_s[tid] = d2;
  }
  __syncthreads();
  if (tid < 152) {
    int j = tid / 8, hh = tid & 7;
    float adj_ = ad_s[j * 8 + hh];
    float ev[19], m = -1e30f;
#pragma unroll
    for (int i = 0; i < 19; i++) {
      float e = lrelu(as_s[i * 8 + hh] + adj_);
      ev[i] = e;
      m = fmaxf(m, e);
    }
    float den = 0.f;
#pragma unroll
    for (int i = 0; i < 19; i++) {
      ev[i] = __expf(ev[i] - m);
      den += ev[i];
    }
    float inv = 1.f / (den + 1e-16f);
    float scj = sc_s[j];
#pragma unroll
    for (int i = 0; i < 19; i++)
      watt[(j * 8 + hh) * 19 + i] = ev[i] * inv * sc_s[i] * scj;
  }
  __syncthreads();
  for (int idx = tid; idx < 19 * 64; idx += 256) {
    int j = idx >> 6, d = idx & 63;
    float acc = 0.f;
#pragma unroll
    for (int hh = 0; hh < 8; hh++) {
      const float* wr = &watt[(j * 8 + hh) * 19];
      float a = 0.f;
#pragma unroll
      for (int i = 0; i < 19; i++) a += wr[i] * h[i * 512 + hh * 64 + d];
      acc += a;
    }
    float om = acc * 0.125f + g1bias[d];
    float v = bg1[d] * om + bb1g[d];
    float sk = skb[d];
    const float* fr = &fb[j * 32];
#pragma unroll
    for (int c = 0; c < 32; c++) sk += fr[c] * skw[c * 64 + d];
    hb[idx] = geluf(v + sk);
  }
  __syncthreads();

  // ---- GAT layer 2 (h/watt/as/ad reused; h1 fully consumed)
  for (int idx = tid; idx < 19 * 512; idx += 256) {
    int i = idx >> 9, o = idx & 511;
    const float* hr = &hb[i * 64];
    float a = 0.f;
#pragma unroll
    for (int c = 0; c < 64; c++) a += hr[c] * g2w[c * 512 + o];
    h[idx] = a;
  }
  __syncthreads();
  if (tid < 152) {
    int i = tid / 8, hh = tid & 7;
    float a = 0.f, d2 = 0.f;
#pragma unroll
    for (int d = 0; d < 64; d++) {
      float hv = h[i * 512 + hh * 64 + d];
      a += hv * g2as[hh * 64 + d];
      d2 += hv * g2ad[hh * 64 + d];
    }
    as_s[tid] = a;
    ad_s[tid] = d2;
  }
  __syncthreads();
  if (tid < 152) {
    int j = tid / 8, hh = tid & 7;
    float adj_ = ad_s[j * 8 + hh];
    float ev[19], m = -1e30f;
#pragma unroll
    for (int i = 0; i < 19; i++) {
      float e = lrelu(as_s[i * 8 + hh] + adj_);
      ev[i] = e;
      m = fmaxf(m, e);
    }
    float den = 0.f;
#pragma unroll
    for (int i = 0; i < 19; i++) {
      ev[i] = __expf(ev[i] - m);
      den += ev[i];
    }
    float inv = 1.f / (den + 1e-16f);
    float scj = sc_s[j];
#pragma unroll
    for (int i = 0; i < 19; i++)
      watt[(j * 8 + hh) * 19 + i] = ev[i] * inv * sc_s[i] * scj;
  }
  __syncthreads();
  for (int idx = tid; idx < 19 * 64; idx += 256) {
    int j = idx >> 6, d = idx & 63;
    float acc = 0.f;
#pragma unroll
    for (int hh = 0; hh < 8; hh++) {
      const float* wr = &watt[(j * 8 + hh) * 19];
      float a = 0.f;
#pragma unroll
      for (int i = 0; i < 19; i++) a += wr[i] * h[i * 512 + hh * 64 + d];
      acc += a;
    }
    float om = acc * 0.125f + g2bias[d];
    float v = bg2[d] * om + bb2g[d] + om;
    hout[idx] = geluf(v);
  }
  __syncthreads();
  // ---- pool + classifier
  if (tid < 64) {
    float a = 0.f;
#pragma unroll
    for (int j = 0; j < 19; j++) a += hout[j * 64 + tid];
    S[OF_GP + tid] = a * (1.f / 19.f);
  }
  __syncthreads();
  if (tid < 64) {
    float a = cb1[tid];
#pragma unroll
    for (int d = 0; d < 64; d++) a += S[OF_GP + d] * cw1[d * 64 + tid];
    S[OF_US + tid] = geluf(a);
  }
  __syncthreads();
  if (tid < 2) {
    float a = cb2[tid];
#pragma unroll
    for (int e = 0; e < 64; e++) a += S[OF_US + e] * cw2[e * 2 + tid];
    out[b * 2 + tid] = a;
  }
}

// ---------------------------------------------------------------------------
extern "C" void kernel_launch(void* const* d_in, const int* in_sizes, int n_in,
                              void* d_out, int out_size, void* d_ws,
                              size_t ws_size, hipStream_t stream) {
  (void)in_sizes; (void)n_in; (void)out_size; (void)ws_size;
  const float* x = (const float*)d_in[0];
  const float* conv1_w = (const float*)d_in[1];
  const float* bn1_g = (const float*)d_in[2];
  const float* bn1_b = (const float*)d_in[3];
  const float* depth_w = (const float*)d_in[4];
  const float* bn2_g = (const float*)d_in[5];
  const float* bn2_b = (const float*)d_in[6];
  const float* se_w1 = (const float*)d_in[7];
  const float* se_w2 = (const float*)d_in[8];
  const float* sep_w = (const float*)d_in[9];
  const float* bn3_g = (const float*)d_in[10];
  const float* bn3_b = (const float*)d_in[11];
  const float* ms_w0 = (const float*)d_in[12];
  const float* ms_g0 = (const float*)d_in[13];
  const float* ms_b0 = (const float*)d_in[14];
  const float* ms_w1 = (const float*)d_in[15];
  const float* ms_g1 = (const float*)d_in[16];
  const float* ms_b1 = (const float*)d_in[17];
  const float* ms_w2 = (const float*)d_in[18];
  const float* ms_g2 = (const float*)d_in[19];
  const float* ms_b2 = (const float*)d_in[20];
  const float* adj_w = (const float*)d_in[21];
  const float* adj_b = (const float*)d_in[22];
  const float* gat1_w = (const float*)d_in[23];
  const float* gat1_as = (const float*)d_in[24];
  const float* gat1_ad = (const float*)d_in[25];
  const float* gat1_bias = (const float*)d_in[26];
  const float* skip1_w = (const float*)d_in[27];
  const float* skip1_b = (const float*)d_in[28];
  const float* bng1_g = (const float*)d_in[29];
  const float* bng1_b = (const float*)d_in[30];
  const float* gat2_w = (const float*)d_in[31];
  const float* gat2_as = (const float*)d_in[32];
  const float* gat2_ad = (const float*)d_in[33];
  const float* gat2_bias = (const float*)d_in[34];
  const float* bng2_g = (const float*)d_in[35];
  const float* bng2_b = (const float*)d_in[36];
  const float* cls_w1 = (const float*)d_in[37];
  const float* cls_b1 = (const float*)d_in[38];
  const float* cls_w2 = (const float*)d_in[39];
  const float* cls_b2 = (const float*)d_in[40];
  // d_in[41] edge_index / d_in[42] batch_idx: fixed dense structure, unused

  float* feat = (float*)d_ws;  // NNODES*32 floats; only z-half is written/read

  hipLaunchKernelGGL(k_ms, dim3(NNODES), dim3(256), 0, stream,
                     x, ms_w0, ms_g0, ms_b0, ms_w1, ms_g1, ms_b1, ms_w2,
                     ms_g2, ms_b2, feat);
  hipLaunchKernelGGL(k_fused, dim3(BATCH), dim3(256), 0, stream,
                     x, conv1_w, bn1_g, bn1_b, depth_w, bn2_g, bn2_b,
                     se_w1, se_w2, sep_w, bn3_g, bn3_b,
                     adj_w, adj_b, gat1_w, gat1_as, gat1_ad, gat1_bias,
                     skip1_w, skip1_b, bng1_g, bng1_b,
                     gat2_w, gat2_as, gat2_ad, gat2_bias, bng2_g, bng2_b,
                     cls_w1, cls_b1, cls_w2, cls_b2, feat, (float*)d_out);
}